// Round 5
// baseline (220.160 us; speedup 1.0000x reference)
//
#include <hip/hip_runtime.h>

typedef __attribute__((ext_vector_type(8))) short s16x8;
typedef __attribute__((ext_vector_type(4))) float f32x4;
typedef __attribute__((ext_vector_type(16))) float f32x16;
typedef __attribute__((ext_vector_type(4))) int i32x4;

// ---- helpers ---------------------------------------------------------------

static __device__ __forceinline__ unsigned short f2bf(float f) {
  unsigned int u = __float_as_uint(f);
  u += 0x7fffu + ((u >> 16) & 1u);           // round-to-nearest-even
  return (unsigned short)(u >> 16);
}

// XOR-swizzled LDS address: row-major, rowbytes = 1<<shift, 16B-slot swizzle
static __device__ __forceinline__ unsigned short* swz(unsigned short* base, int row,
                                                      int shift, int byte_in_row) {
  int b = (row << shift) + (byte_in_row ^ ((row & 7) << 4));
  return (unsigned short*)((char*)base + b);
}

static __device__ __forceinline__ s16x8 pack8(float4 a, float4 b) {
  s16x8 p;
  p[0] = (short)f2bf(a.x); p[1] = (short)f2bf(a.y);
  p[2] = (short)f2bf(a.z); p[3] = (short)f2bf(a.w);
  p[4] = (short)f2bf(b.x); p[5] = (short)f2bf(b.y);
  p[6] = (short)f2bf(b.z); p[7] = (short)f2bf(b.w);
  return p;
}

static __device__ __forceinline__ int cvtpk(float a, float b) {
  int r;
  asm("v_cvt_pk_bf16_f32 %0, %1, %2" : "=v"(r) : "v"(a), "v"(b));
  return r;
}

static __device__ __forceinline__ void plswap(int& x, int& y) {
  asm("v_permlane32_swap_b32 %0, %1" : "+v"(x), "+v"(y));
}

// async global->LDS, 16B per lane; LDS dest is wave-uniform base + lane*16
#define GLDS(gp, lp) __builtin_amdgcn_global_load_lds(                        \
    (const __attribute__((address_space(1))) void*)(gp),                      \
    (__attribute__((address_space(3))) void*)(lp), 16, 0, 0)

// stage one 16KB tile image (already swizzled in ws): wave w copies 4KB
#define STAGE(ldsbase, gtile) do {                                            \
    const char* _g = (const char*)(gtile) + (w << 12) + (lane << 4);          \
    char* _l = (char*)(ldsbase) + (w << 12);                                  \
    GLDS(_g,        _l);                                                      \
    GLDS(_g + 1024, _l + 1024);                                               \
    GLDS(_g + 2048, _l + 2048);                                               \
    GLDS(_g + 3072, _l + 3072);                                               \
  } while (0)

// ---- pack kernel ------------------------------------------------------------
// Per (bh,t): K 64x128 bf16 row-major (256B rows), V transposed to 128x64
// (128B rows). Both stored PRE-XOR-SWIZZLED so linear global_load_lds into LDS
// reproduces the swizzled image.

__global__ void pack_kv(const float* __restrict__ Kg, const float* __restrict__ Vg,
                        unsigned short* __restrict__ Kw, unsigned short* __restrict__ Vw) {
  __shared__ float Vs[8192];
  const int blk = (int)blockIdx.x;          // bh*32 + t
  const float* Kb = Kg + ((size_t)blk << 13);
  const float* Vb = Vg + ((size_t)blk << 13);
  unsigned short* Ko = Kw + ((size_t)blk << 13);
  unsigned short* Vo = Vw + ((size_t)blk << 13);
  int c = (int)threadIdx.x;
  #pragma unroll
  for (int it = 0; it < 4; ++it, c += 256) {
    int r = c >> 4, c8 = (c & 15) << 3;
    int dst = r * 128 + ((((c8 << 1)) ^ ((r & 7) << 4)) >> 1);
    const float4* s4 = (const float4*)(Kb + r * 128 + c8);
    *(s16x8*)(Ko + dst) = pack8(s4[0], s4[1]);
  }
  c = (int)threadIdx.x;
  #pragma unroll
  for (int it = 0; it < 8; ++it, c += 256)
    *(float4*)(Vs + (c << 2)) = *(const float4*)(Vb + (c << 2));
  __syncthreads();
  c = (int)threadIdx.x;
  #pragma unroll
  for (int it = 0; it < 4; ++it, c += 256) {
    int d = c & 127, j0 = (c >> 7) << 3;
    s16x8 p;
    #pragma unroll
    for (int e = 0; e < 8; ++e) p[e] = (short)f2bf(Vs[(j0 + e) * 128 + d]);
    int dst = d * 64 + ((((j0 << 1)) ^ ((d & 7) << 4)) >> 1);
    *(s16x8*)(Vo + dst) = p;
  }
}

// ---- main kernel ------------------------------------------------------------
// B=2 H=16 S=2048 D=128. 256 thr = 4 waves; wave (qh=w>>1, jh=w&1) owns a
// 32q x 32j quadrant of the 64x64 block tile. Swapped QK^T: mfma(K, Q) puts
// P[q=lane&31][j in regs]; softmax + PV A-frags fully in-register.
// Fixed-shift softmax (shift=8). Regimes per (t, wave):
//   FAR  (t<=qt-3): prior < 1e-14 -> skip prior & mask
//   NEAR (qt-2..qt-1, or diag with jh<qh): prior, no mask
//   DIAG (t==qt, jh==qh): prior + causal mask
//   SKIP (t==qt, jh>qh): fully masked -> zeros

__global__ __launch_bounds__(256, 2)
void gpsdpa4(const float* __restrict__ Qg, const unsigned short* __restrict__ Kw,
             const unsigned short* __restrict__ Vw, float* __restrict__ Og,
             float* __restrict__ Ag) {
  __shared__ alignas(16) unsigned short KV[4][8192];  // 64KB: K/V tile buffers
  __shared__ float red[128];

  const int tid  = (int)threadIdx.x;
  const int w    = tid >> 6;
  const int lane = tid & 63;
  const int l31  = lane & 31;
  const int hi   = lane >> 5;
  const int qh   = w >> 1;
  const int jh   = w & 1;

  const int bh = (int)blockIdx.x & 31;
  const int qt = 31 - ((int)blockIdx.x >> 5);
  const int h  = bh & 15;
  const int q0 = qt << 6;

  const float* Qb = Qg + ((size_t)bh << 18) + ((size_t)q0 << 7);
  const unsigned short* Kb = Kw + ((size_t)(bh << 5) << 13);
  const unsigned short* Vb = Vw + ((size_t)(bh << 5) << 13);
  float* Ob = Og + ((size_t)bh << 18) + ((size_t)q0 << 7);
  float* Ab = Ag + ((size_t)bh << 22);

  const float sig = (float)(h + 1);
  const float cst = -1.0f / (2.0f * sig * sig);
  const float scale = 0.08838834764831845f;  // 1/sqrt(128)

  // Q B-frags: lane owns q = qh*32 + l31; bQ[dk] = Q[q][dk*16 + hi*8 .. +8]
  s16x8 bQ[8];
  {
    const float* qr = Qb + ((qh << 5) + l31) * 128 + (hi << 3);
    #pragma unroll
    for (int dk = 0; dk < 8; ++dk) {
      const float4* s4 = (const float4*)(qr + (dk << 4));
      bQ[dk] = pack8(s4[0], s4[1]);
    }
  }

  const int iq   = q0 + (qh << 5) + l31;     // this lane's attention row
  const int krow = (jh << 5) + l31;
  const int kswz = (krow & 7) << 4;

  // ---------------- pass 1: per-lane row sums of exp(s - 8) ----------------
  float psum = 0.f;
  const int nst = (qt >> 1) + 1;
  STAGE(&KV[0][0], Kb);
  STAGE(&KV[1][0], Kb + ((size_t)1 << 13));
  for (int s = 0; s < nst; ++s) {
    const int cur = s & 1;
    __syncthreads();
    if (s + 1 < nst) {
      STAGE(&KV[(cur ^ 1) << 1][0],       Kb + ((size_t)(2 * s + 2) << 13));
      STAGE(&KV[((cur ^ 1) << 1) + 1][0], Kb + ((size_t)(2 * s + 3) << 13));
    }
    #pragma unroll
    for (int half = 0; half < 2; ++half) {
      const int t = 2 * s + half;
      if (t > qt) break;
      if ((t == qt) && (jh > qh)) continue;   // fully masked quadrant
      const char* KtC = (const char*)&KV[(cur << 1) + half][0] + krow * 256;

      f32x16 acc = (f32x16)0.0f;
      #pragma unroll
      for (int dk = 0; dk < 8; ++dk) {
        s16x8 aK = *(const s16x8*)(KtC + (((dk << 5) + (hi << 4)) ^ kswz));
        acc = __builtin_amdgcn_mfma_f32_32x32x16_bf16(aK, bQ[dk], acc, 0, 0, 0);
      }

      if (t <= qt - 3) {                     // FAR
        #pragma unroll
        for (int r = 0; r < 16; ++r)
          psum += __expf(fmaf(acc[r], scale, -8.0f));
      } else if (t < qt || jh < qh) {        // NEAR
        #pragma unroll
        for (int r = 0; r < 16; ++r) {
          int j = (t << 6) + (jh << 5) + (r & 3) + ((r >> 2) << 3) + (hi << 2);
          float fd = (float)(iq - j);
          psum += __expf(fmaf(acc[r], scale, __expf(fd * fd * cst) - 8.0f));
        }
      } else {                               // DIAG
        #pragma unroll
        for (int r = 0; r < 16; ++r) {
          int j = (t << 6) + (jh << 5) + (r & 3) + ((r >> 2) << 3) + (hi << 2);
          int dist = iq - j;
          float fd = (float)dist;
          float x = fmaf(acc[r], scale, __expf(fd * fd * cst) - 8.0f);
          psum += (dist >= 0) ? __expf(x) : 0.f;
        }
      }
    }
  }

  // row total: other lane-half (same q), then partner wave (other jh)
  psum += __shfl_xor(psum, 32, 64);
  __syncthreads();
  if (lane < 32) red[(((qh << 1) | jh) << 5) + l31] = psum;
  __syncthreads();
  const float tot = psum + red[(((qh << 1) | (jh ^ 1)) << 5) + l31];
  const float lrs = -8.0f - __logf(tot);     // fold 1/sum into exp bias

  // ---------------- pass 2: probs -> attn + PV ----------------
  f32x16 oacc[4];
  #pragma unroll
  for (int dn = 0; dn < 4; ++dn) oacc[dn] = (f32x16)0.0f;

  __syncthreads();                           // pass-1 reads of KV done
  STAGE(&KV[0][0], Kb);                      // K tile0
  STAGE(&KV[2][0], Vb);                      // V tile0

  for (int t = 0; t <= qt; ++t) {
    const int cur = t & 1;
    __syncthreads();
    if (t < qt) {
      STAGE(&KV[cur ^ 1][0],       Kb + ((size_t)(t + 1) << 13));
      STAGE(&KV[2 + (cur ^ 1)][0], Vb + ((size_t)(t + 1) << 13));
    }

    const bool skipq = (t == qt) && (jh > qh);
    float p[16];
    if (!skipq) {
      const char* KtC = (const char*)&KV[cur][0] + krow * 256;
      f32x16 acc = (f32x16)0.0f;
      #pragma unroll
      for (int dk = 0; dk < 8; ++dk) {
        s16x8 aK = *(const s16x8*)(KtC + (((dk << 5) + (hi << 4)) ^ kswz));
        acc = __builtin_amdgcn_mfma_f32_32x32x16_bf16(aK, bQ[dk], acc, 0, 0, 0);
      }
      if (t <= qt - 3) {                     // FAR
        #pragma unroll
        for (int r = 0; r < 16; ++r)
          p[r] = __expf(fmaf(acc[r], scale, lrs));
      } else if (t < qt || jh < qh) {        // NEAR
        #pragma unroll
        for (int r = 0; r < 16; ++r) {
          int j = (t << 6) + (jh << 5) + (r & 3) + ((r >> 2) << 3) + (hi << 2);
          float fd = (float)(iq - j);
          p[r] = __expf(fmaf(acc[r], scale, __expf(fd * fd * cst) + lrs));
        }
      } else {                               // DIAG
        #pragma unroll
        for (int r = 0; r < 16; ++r) {
          int j = (t << 6) + (jh << 5) + (r & 3) + ((r >> 2) << 3) + (hi << 2);
          int dist = iq - j;
          float fd = (float)dist;
          float x = fmaf(acc[r], scale, __expf(fd * fd * cst) + lrs);
          p[r] = (dist >= 0) ? __expf(x) : 0.f;
        }
      }
    } else {
      #pragma unroll
      for (int r = 0; r < 16; ++r) p[r] = 0.f;
    }

    // attn store: reg-quad (r&3) = 4 consecutive j -> coalesced float4 stores
    {
      float* arow = Ab + (size_t)iq * 2048 + (t << 6) + (jh << 5) + (hi << 2);
      *(float4*)(arow)      = make_float4(p[0],  p[1],  p[2],  p[3]);
      *(float4*)(arow + 8)  = make_float4(p[4],  p[5],  p[6],  p[7]);
      *(float4*)(arow + 16) = make_float4(p[8],  p[9],  p[10], p[11]);
      *(float4*)(arow + 24) = make_float4(p[12], p[13], p[14], p[15]);
    }

    // PV: A = P (in-register, cvt_pk + permlane32_swap), B = V^T tile from LDS
    if (!skipq) {
      const char* VtC = (const char*)&KV[2 + cur][0];
      #pragma unroll
      for (int ks = 0; ks < 2; ++ks) {
        int x0 = cvtpk(p[8 * ks + 0], p[8 * ks + 1]);
        int x1 = cvtpk(p[8 * ks + 2], p[8 * ks + 3]);
        int y0 = cvtpk(p[8 * ks + 4], p[8 * ks + 5]);
        int y1 = cvtpk(p[8 * ks + 6], p[8 * ks + 7]);
        plswap(x0, y0);
        plswap(x1, y1);
        i32x4 pk4; pk4[0] = x0; pk4[1] = x1; pk4[2] = y0; pk4[3] = y1;
        s16x8 pa = *(s16x8*)&pk4;
        #pragma unroll
        for (int dn = 0; dn < 4; ++dn) {
          int vrow = (dn << 5) + l31;
          s16x8 vb = *(const s16x8*)((const char*)VtC + vrow * 128 +
                       (((jh << 6) + (ks << 5) + (hi << 4)) ^ ((vrow & 7) << 4)));
          oacc[dn] = __builtin_amdgcn_mfma_f32_32x32x16_bf16(pa, vb, oacc[dn], 0, 0, 0);
        }
      }
    }
  }

  // ---------------- context: sum jh pair via LDS, coalesced store -----------
  __syncthreads();                           // KV free now
  float* cts = (float*)&KV[0][0];
  if (jh == 1) {
    #pragma unroll
    for (int dn = 0; dn < 4; ++dn)
      #pragma unroll
      for (int r = 0; r < 16; ++r) {
        int qrow = (r & 3) + ((r >> 2) << 3) + (hi << 2);
        cts[(qh << 12) + qrow * 128 + (dn << 5) + l31] = oacc[dn][r];
      }
  }
  __syncthreads();
  if (jh == 0) {
    #pragma unroll
    for (int dn = 0; dn < 4; ++dn)
      #pragma unroll
      for (int r = 0; r < 16; ++r) {
        int qrow = (r & 3) + ((r >> 2) << 3) + (hi << 2);
        float v = oacc[dn][r] + cts[(qh << 12) + qrow * 128 + (dn << 5) + l31];
        Ob[(size_t)((qh << 5) + qrow) * 128 + (dn << 5) + l31] = v;
      }
  }

  // zero-fill attn tiles j-tile > qt (upper triangle)
  const float4 z4 = make_float4(0.f, 0.f, 0.f, 0.f);
  for (int tt = qt + 1; tt < 32; ++tt) {
    float4* dst = (float4*)(Ab + (size_t)q0 * 2048 + (tt << 6));
    int f = tid;
    #pragma unroll
    for (int k = 0; k < 4; ++k, f += 256) {
      int r = f >> 4, cc = f & 15;
      dst[(size_t)r * 512 + cc] = z4;
    }
  }
}

// ---- fallback kernel (round-1, used when ws too small) ----------------------

__global__ __launch_bounds__(256, 2)
void gpsdpa_fb(const float* __restrict__ Qg, const float* __restrict__ Kg,
               const float* __restrict__ Vg, float* __restrict__ Og,
               float* __restrict__ Ag) {
  __shared__ alignas(16) unsigned short Qs[64 * 128];
  __shared__ alignas(16) unsigned short Ksl[64 * 128];
  __shared__ alignas(16) unsigned short Vtl[128 * 64];
  __shared__ alignas(16) unsigned short Ps[4][16 * 64];
  __shared__ float gtab[2048];

  const int tid  = (int)threadIdx.x;
  const int w    = tid >> 6;
  const int lane = tid & 63;
  const int l15  = lane & 15;
  const int g    = lane >> 4;

  const int bh = (int)blockIdx.x & 31;
  const int qt = 31 - ((int)blockIdx.x >> 5);
  const int h  = bh & 15;
  const int q0 = qt << 6;

  const size_t base = (size_t)bh << 18;
  const float* Qb = Qg + base + (size_t)q0 * 128;
  const float* Kb = Kg + base;
  const float* Vb = Vg + base;
  float* Ob = Og + base;
  float* Ab = Ag + ((size_t)bh << 22);

  {
    float sig = (float)(h + 1);
    float c = -1.0f / (2.0f * sig * sig);
    for (int d = tid; d < 2048; d += 256) {
      float fd = (float)d;
      gtab[d] = __expf(fd * fd * c);
    }
  }

  {
    int c = tid;
    #pragma unroll
    for (int it = 0; it < 4; ++it, c += 256) {
      int r = c >> 4, c8 = (c & 15) << 3;
      const float4* s4 = (const float4*)(Qb + (size_t)r * 128 + c8);
      *(s16x8*)swz(Qs, r, 8, c8 * 2) = pack8(s4[0], s4[1]);
    }
  }
  __syncthreads();

  s16x8 aQ[4];
  #pragma unroll
  for (int kc = 0; kc < 4; ++kc)
    aQ[kc] = *(const s16x8*)swz(Qs, (w << 4) + l15, 8, (kc << 6) + (g << 4));

  const float scale = 0.08838834764831845f;
  const int ibase = q0 + (w << 4) + (g << 2);

  float m_r[4], ls_r[4];
  #pragma unroll
  for (int r = 0; r < 4; ++r) { m_r[r] = -3.0e38f; ls_r[r] = 0.0f; }

  const f32x4 fzero = {0.f, 0.f, 0.f, 0.f};

  for (int t = 0; t <= qt; ++t) {
    __syncthreads();
    {
      int c = tid;
      #pragma unroll
      for (int it = 0; it < 4; ++it, c += 256) {
        int r = c >> 4, c8 = (c & 15) << 3;
        const float4* s4 = (const float4*)(Kb + (size_t)((t << 6) + r) * 128 + c8);
        *(s16x8*)swz(Ksl, r, 8, c8 * 2) = pack8(s4[0], s4[1]);
      }
    }
    __syncthreads();

    f32x4 acc[4];
    #pragma unroll
    for (int n = 0; n < 4; ++n) acc[n] = fzero;
    #pragma unroll
    for (int kc = 0; kc < 4; ++kc) {
      #pragma unroll
      for (int n = 0; n < 4; ++n) {
        s16x8 bK = *(const s16x8*)swz(Ksl, (n << 4) + l15, 8, (kc << 6) + (g << 4));
        acc[n] = __builtin_amdgcn_mfma_f32_16x16x32_bf16(aQ[kc], bK, acc[n], 0, 0, 0);
      }
    }

    const int jb = (t << 6) + l15;
    #pragma unroll
    for (int r = 0; r < 4; ++r) {
      const int i = ibase + r;
      float sv[4];
      float mx = -3.0e38f;
      #pragma unroll
      for (int n = 0; n < 4; ++n) {
        int dist = i - (jb + (n << 4));
        float x = (dist >= 0) ? (acc[n][r] * scale + gtab[dist]) : -1.0e9f;
        sv[n] = x;
        mx = fmaxf(mx, x);
      }
      #pragma unroll
      for (int mk = 1; mk < 16; mk <<= 1) mx = fmaxf(mx, __shfl_xor(mx, mk, 64));
      float mn = fmaxf(m_r[r], mx);
      float sm = 0.f;
      #pragma unroll
      for (int n = 0; n < 4; ++n) sm += __expf(sv[n] - mn);
      #pragma unroll
      for (int mk = 1; mk < 16; mk <<= 1) sm += __shfl_xor(sm, mk, 64);
      ls_r[r] = ls_r[r] * __expf(m_r[r] - mn) + sm;
      m_r[r] = mn;
    }
  }

  float rls[4];
  #pragma unroll
  for (int r = 0; r < 4; ++r) rls[r] = 1.0f / ls_r[r];

  f32x4 oacc[8];
  #pragma unroll
  for (int dn = 0; dn < 8; ++dn) oacc[dn] = fzero;

  unsigned short* Pw = &Ps[w][0];

  for (int t = 0; t <= qt; ++t) {
    __syncthreads();
    {
      int c = tid;
      #pragma unroll
      for (int it = 0; it < 4; ++it, c += 256) {
        int r = c >> 4, c8 = (c & 15) << 3;
        const float4* s4 = (const float4*)(Kb + (size_t)((t << 6) + r) * 128 + c8);
        *(s16x8*)swz(Ksl, r, 8, c8 * 2) = pack8(s4[0], s4[1]);
      }
      c = tid;
      #pragma unroll
      for (int it = 0; it < 4; ++it, c += 256) {
        int d = c & 127, j0 = (c >> 7) << 3;
        const float* vs = Vb + (size_t)((t << 6) + j0) * 128 + d;
        s16x8 p;
        #pragma unroll
        for (int e = 0; e < 8; ++e) p[e] = (short)f2bf(vs[(size_t)e * 128]);
        *(s16x8*)swz(Vtl, d, 7, j0 * 2) = p;
      }
    }
    __syncthreads();

    f32x4 acc[4];
    #pragma unroll
    for (int n = 0; n < 4; ++n) acc[n] = fzero;
    #pragma unroll
    for (int kc = 0; kc < 4; ++kc) {
      #pragma unroll
      for (int n = 0; n < 4; ++n) {
        s16x8 bK = *(const s16x8*)swz(Ksl, (n << 4) + l15, 8, (kc << 6) + (g << 4));
        acc[n] = __builtin_amdgcn_mfma_f32_16x16x32_bf16(aQ[kc], bK, acc[n], 0, 0, 0);
      }
    }

    const int jb = (t << 6) + l15;
    #pragma unroll
    for (int r = 0; r < 4; ++r) {
      const int i = ibase + r;
      float* arow = Ab + (size_t)i * 2048 + (t << 6) + l15;
      #pragma unroll
      for (int n = 0; n < 4; ++n) {
        int dist = i - (jb + (n << 4));
        float x = (dist >= 0) ? (acc[n][r] * scale + gtab[dist]) : -1.0e9f;
        float p = __expf(x - m_r[r]) * rls[r];
        arow[n << 4] = p;
        *swz(Pw, (g << 2) + r, 7, ((n << 4) + l15) << 1) = f2bf(p);
      }
    }

    #pragma unroll
    for (int kc2 = 0; kc2 < 2; ++kc2) {
      s16x8 pa = *(const s16x8*)swz(Pw, l15, 7, (kc2 << 6) + (g << 4));
      #pragma unroll
      for (int dn = 0; dn < 8; ++dn) {
        s16x8 vb = *(const s16x8*)swz(Vtl, (dn << 4) + l15, 7, (kc2 << 6) + (g << 4));
        oacc[dn] = __builtin_amdgcn_mfma_f32_16x16x32_bf16(pa, vb, oacc[dn], 0, 0, 0);
      }
    }
  }

  #pragma unroll
  for (int dn = 0; dn < 8; ++dn) {
    #pragma unroll
    for (int r = 0; r < 4; ++r) {
      Ob[(size_t)(ibase + r) * 128 + (dn << 4) + l15] = oacc[dn][r];
    }
  }

  const int jmax = (qt + 1) << 6;
  if (jmax < 2048) {
    for (int r = 0; r < 64; ++r) {
      float4* dst = (float4*)(Ab + (size_t)(q0 + r) * 2048);
      for (int cv = (jmax >> 2) + tid; cv < 512; cv += 256) {
        dst[cv] = make_float4(0.f, 0.f, 0.f, 0.f);
      }
    }
  }
}

// ---- launch ----------------------------------------------------------------

extern "C" void kernel_launch(void* const* d_in, const int* in_sizes, int n_in,
                              void* d_out, int out_size, void* d_ws, size_t ws_size,
                              hipStream_t stream) {
  (void)in_sizes; (void)n_in; (void)out_size;
  const float* Q = (const float*)d_in[0];
  const float* K = (const float*)d_in[1];
  const float* V = (const float*)d_in[2];
  float* ctx  = (float*)d_out;
  float* attn = ctx + (size_t)2 * 16 * 2048 * 128;
  dim3 grid(1024), block(256);

  const size_t NEED = (size_t)2 << 24;  // 33.55 MB: Kw + Vtw bf16 images
  if (ws_size >= NEED) {
    unsigned short* Kw = (unsigned short*)d_ws;
    unsigned short* Vw = Kw + ((size_t)1 << 23);
    pack_kv<<<grid, block, 0, stream>>>(K, V, Kw, Vw);
    gpsdpa4<<<grid, block, 0, stream>>>(Q, Kw, Vw, ctx, attn);
  } else {
    gpsdpa_fb<<<grid, block, 0, stream>>>(Q, K, V, ctx, attn);
  }
}